// Round 5
// baseline (752.025 us; speedup 1.0000x reference)
//
#include <hip/hip_runtime.h>
#include <hip/hip_bf16.h>

#define Hn 8
#define Fn 768
#define Dn 128
#define En 256
#define Ln 13
#define Bn 8
#define Tn 1000
#define TPn 1024
#define NCOR 8128

typedef float f32x4 __attribute__((ext_vector_type(4)));
typedef __bf16 bf16x8 __attribute__((ext_vector_type(8)));
typedef unsigned short u16;

static __device__ __forceinline__ u16 f2bf(float f) {
  __hip_bfloat16 h = __float2bfloat16(f);
  return __builtin_bit_cast(u16, h);
}
static __device__ __forceinline__ float bf2f(u16 u) {
  return __bfloat162float(__builtin_bit_cast(__hip_bfloat16, u));
}

// async global->LDS, 16B per lane. LDS dest must be wave-uniform base; HW adds lane*16.
static __device__ __forceinline__ void gload_lds16(const u16* g, u16* lds_wave_base) {
  __builtin_amdgcn_global_load_lds(
      (const __attribute__((address_space(1))) unsigned int*)g,
      (__attribute__((address_space(3))) unsigned int*)lds_wave_base, 16, 0, 0);
}

// ---------------------------------------------------------------- k1: l-reduce (+folded prep)
// GRID: (t-block 32, f-block 24, BG).  t fastest => lin%8 == t-block%8, so ALL
// f-chunks of a given kv_raw row land on the same XCD's L2 and merge into full
// 128B lines before writeback. x loads are non-temporal (read-once, 319MB).
__global__ __launch_bounds__(256) void k1_raw(
    const float* __restrict__ x,
    const float* __restrict__ wk, const float* __restrict__ wv,
    const float* __restrict__ Wk, const float* __restrict__ Wv,
    u16* __restrict__ kv_raw, u16* __restrict__ Wbf,
    float* __restrict__ s1, float* __restrict__ s2,
    int b0, int BG) {
  __shared__ float kvw[16 * Ln];
  __shared__ u16 res[16 * 32 * 34];  // 34816 B; row stride 34 (17 uints, odd)
  int tid = threadIdx.x;
  if (tid < 16) {
    int kvi = tid >> 3, h = tid & 7;
    const float* w = (kvi ? wv : wk) + h * Ln;
    float m = -1e30f;
    for (int l = 0; l < Ln; ++l) m = fmaxf(m, w[l]);
    float e[Ln], s = 0.f;
    for (int l = 0; l < Ln; ++l) { e[l] = expf(w[l] - m); s += e[l]; }
    for (int l = 0; l < Ln; ++l) kvw[tid * Ln + l] = e[l] / s;
  }
  if (b0 == 0) {  // folded k0 work; only the first batch-group pass
    int nb = gridDim.x * gridDim.y * gridDim.z;
    int lin = blockIdx.x + gridDim.x * (blockIdx.y + gridDim.y * blockIdx.z);
    int n = 2 * Hn * Dn * Fn;  // 1572864 == 6144*256: one elem/thread at BG=8
    for (int i = lin * 256 + tid; i < n; i += nb * 256) {
      float v = (i < Hn * Dn * Fn) ? Wk[i] : Wv[i - Hn * Dn * Fn];
      Wbf[i] = f2bf(v);
    }
    int ns = 2 * Bn * Hn * Dn;
    for (int i = lin * 256 + tid; i < ns; i += nb * 256) { s1[i] = 0.f; s2[i] = 0.f; }
  }
  int t0 = blockIdx.x * 32, f0 = blockIdx.y * 32;
  int b_l = blockIdx.z, b = b0 + b_l;
  int fl = tid & 31, tq = tid >> 5;
  int tbase = t0 + tq * 4;
  bool valid = (tbase < Tn);  // Tn%4==0 -> quads never straddle
  f32x4 xq[13];
  if (valid) {
    const f32x4* xp = (const f32x4*)(x + ((size_t)(b * Fn + f0 + fl) * Tn + tbase) * Ln);
#pragma unroll
    for (int i = 0; i < 13; ++i) xq[i] = __builtin_nontemporal_load(xp + i);
  }
  __syncthreads();
  const float* xf = (const float*)xq;
  for (int o = 0; o < 16; ++o) {
    float a0 = 0.f, a1 = 0.f, a2 = 0.f, a3 = 0.f;
    if (valid) {
#pragma unroll
      for (int l = 0; l < Ln; ++l) {
        float w = kvw[o * Ln + l];
        a0 += xf[l] * w;
        a1 += xf[Ln + l] * w;
        a2 += xf[2 * Ln + l] * w;
        a3 += xf[3 * Ln + l] * w;
      }
    }
    int rb = o * 1088 + tq * 4 * 34 + fl;
    res[rb] = f2bf(a0);
    res[rb + 34] = f2bf(a1);
    res[rb + 68] = f2bf(a2);
    res[rb + 102] = f2bf(a3);
  }
  __syncthreads();
  int part = tid & 3;
#pragma unroll
  for (int it = 0; it < 8; ++it) {
    int r = (tid >> 2) + it * 64;
    int o = r >> 5, tl = r & 31;
    int kv = o >> 3, h = o & 7;
    const u16* src = res + o * 1088 + tl * 34 + part * 8;
    uint4 v;
    v.x = *(const unsigned*)(src + 0);
    v.y = *(const unsigned*)(src + 2);
    v.z = *(const unsigned*)(src + 4);
    v.w = *(const unsigned*)(src + 6);
    u16* dst = kv_raw + (((size_t)(kv * BG + b_l) * Hn + h) * TPn + t0 + tl) * Fn + f0 + part * 8;
    *reinterpret_cast<uint4*>(dst) = v;
  }
}

// ---------------------------------------------------------------- k2: main GEMM
// 128x128 tile, BK=32, bf16 MFMA, 2-phase dbuf. GRID: (bh fastest, t, kv) so all
// t-blocks of one (bh,kv) share an XCD -> B-slab fetched once per XCD.
// Fused: scores = q.K for kv==0 tiles.
__global__ __launch_bounds__(256) void k2_gemm(
    const u16* __restrict__ kv_raw, const u16* __restrict__ Wbf,
    const float* __restrict__ bk, const float* __restrict__ bv,
    const float* __restrict__ qg,
    u16* __restrict__ mhT, float* __restrict__ s1buf, float* __restrict__ s2buf,
    float* __restrict__ scores, int b0, int BG) {
  __shared__ __align__(16) char ldsbuf[33280];
  __shared__ float qsh[Dn];
  u16* As0 = (u16*)ldsbuf;             // [128 t][32 f]  8KB
  u16* Bs0 = (u16*)(ldsbuf + 8192);    // [128 d][32 f]  8KB
  u16* As1 = (u16*)(ldsbuf + 16384);
  u16* Bs1 = (u16*)(ldsbuf + 24576);
  u16* Cst = (u16*)ldsbuf;             // [128 t][130] (reused after K-loop)
  int tid = threadIdx.x, lane = tid & 63, w = tid >> 6;
  int bh_lin = blockIdx.x;
  int b_l = bh_lin / Hn, h = bh_lin % Hn;
  int t0 = blockIdx.y * 128;
  int kv = blockIdx.z;
  int b = b0 + b_l;
  if (tid < Dn) qsh[tid] = qg[h * Dn + tid];
  const u16* Abase = kv_raw + ((size_t)(kv * BG + b_l) * Hn + h) * TPn * Fn + (size_t)t0 * Fn;
  const u16* Bbase = Wbf + ((size_t)(kv * Hn + h)) * Dn * Fn;
  f32x4 acc[4][4];
#pragma unroll
  for (int mi = 0; mi < 4; ++mi)
#pragma unroll
    for (int ni = 0; ni < 4; ++ni) acc[mi][ni] = (f32x4){0.f, 0.f, 0.f, 0.f};
  int wm = (w >> 1) * 64, wn = (w & 1) * 64;
  int lin0 = tid, lin1 = tid + 256;
  int row0 = lin0 >> 2, part0 = lin0 & 3;
  int row1 = lin1 >> 2, part1 = lin1 & 3;
  int wb0 = (w * 64) * 8, wb1 = (256 + w * 64) * 8;  // wave-uniform LDS elem base

  auto STAGE = [&](int f0, u16* Ad, u16* Bd) {
    gload_lds16(Abase + (size_t)row0 * Fn + f0 + part0 * 8, Ad + wb0);
    gload_lds16(Abase + (size_t)row1 * Fn + f0 + part1 * 8, Ad + wb1);
    gload_lds16(Bbase + (size_t)row0 * Fn + f0 + part0 * 8, Bd + wb0);
    gload_lds16(Bbase + (size_t)row1 * Fn + f0 + part1 * 8, Bd + wb1);
  };
  auto COMPUTE = [&](const u16* Ac, const u16* Bc) {
    bf16x8 af[4], bg[4];
#pragma unroll
    for (int mi = 0; mi < 4; ++mi)
      af[mi] = *(const bf16x8*)(Ac + (wm + mi * 16 + (lane & 15)) * 32 + (lane >> 4) * 8);
#pragma unroll
    for (int ni = 0; ni < 4; ++ni)
      bg[ni] = *(const bf16x8*)(Bc + (wn + ni * 16 + (lane & 15)) * 32 + (lane >> 4) * 8);
#pragma unroll
    for (int mi = 0; mi < 4; ++mi)
#pragma unroll
      for (int ni = 0; ni < 4; ++ni)
        acc[mi][ni] = __builtin_amdgcn_mfma_f32_16x16x32_bf16(af[mi], bg[ni], acc[mi][ni], 0, 0, 0);
  };

  STAGE(0, As0, Bs0);
  __syncthreads();  // covers qsh + prologue stage
  for (int f0 = 0; f0 < Fn; f0 += 64) {
    if (f0 + 32 < Fn) STAGE(f0 + 32, As1, Bs1);
    COMPUTE(As0, Bs0);
    __syncthreads();
    if (f0 + 64 < Fn) STAGE(f0 + 64, As0, Bs0);
    COMPUTE(As1, Bs1);
    __syncthreads();
  }

  float bias[4];
  const float* bptr = (kv ? bv : bk) + h * Dn;
#pragma unroll
  for (int ni = 0; ni < 4; ++ni) bias[ni] = bptr[wn + ni * 16 + (lane & 15)];
#pragma unroll
  for (int mi = 0; mi < 4; ++mi)
#pragma unroll
    for (int ni = 0; ni < 4; ++ni)
#pragma unroll
      for (int r = 0; r < 4; ++r) {
        int row = wm + mi * 16 + (lane >> 4) * 4 + r;  // t-local
        int col = wn + ni * 16 + (lane & 15);          // d
        float v = acc[mi][ni][r] + bias[ni];
        if (t0 + row >= Tn) v = 0.f;                   // zero-pad rows (Gram-safe)
        Cst[row * 130 + col] = f2bf(v);
      }
  __syncthreads();
  int d = tid >> 1, half = tid & 1;
  u16* orow = mhT + (((size_t)(kv * Bn + b) * Hn + h) * Dn + d) * TPn + t0;
  float ssum = 0.f, ssq = 0.f;
#pragma unroll
  for (int j = 0; j < 8; ++j) {
    int tb = half * 64 + j * 8;
    u16 pk[8];
#pragma unroll
    for (int ii = 0; ii < 8; ++ii) {
      u16 ub = Cst[(tb + ii) * 130 + d];
      pk[ii] = ub;
      float vr = bf2f(ub);
      ssum += vr;
      ssq += vr * vr;
    }
    uint4 v4;
    v4.x = (unsigned)pk[0] | ((unsigned)pk[1] << 16);
    v4.y = (unsigned)pk[2] | ((unsigned)pk[3] << 16);
    v4.z = (unsigned)pk[4] | ((unsigned)pk[5] << 16);
    v4.w = (unsigned)pk[6] | ((unsigned)pk[7] << 16);
    *reinterpret_cast<uint4*>(orow + tb) = v4;
  }
  int sidx = ((kv * Bn + b) * Hn + h) * Dn + d;
  atomicAdd(&s1buf[sidx], ssum);
  atomicAdd(&s2buf[sidx], ssq);

  // ---- fused attention scores (kv==0 only): s[t] = q . K[t,:]
  if (kv == 0) {
    int t = tid >> 1, hf = tid & 1;
    float s = 0.f;
    const u16* crow = Cst + t * 130 + hf * 64;
    const float* qh = qsh + hf * 64;
#pragma unroll
    for (int dd = 0; dd < 64; ++dd) s += qh[dd] * bf2f(crow[dd]);
    s += __shfl_xor(s, 1);
    if (hf == 0)
      scores[((size_t)b * Hn + h) * TPn + t0 + t] =
          (t0 + t < Tn) ? s * 0.088388347648318447f : -1e30f;
  }
}

// ---------------------------------------------------------------- k34: merged Gram-direct + PV
// blocks 0..127: Gram half (bh, rh): rows [rh*64,+64) x cols [0,128) over full T
//   in-register (V read 2x instead of 4x), normalized in-block, written to corr.
//   Long blocks first in dispatch order.
// blocks 128..383: softmax+PV (d-split x4), wave-shuffle reductions.
__global__ __launch_bounds__(256) void k34(
    const u16* __restrict__ mhT, const float* __restrict__ scores,
    const float* __restrict__ s1buf, const float* __restrict__ s2buf,
    float* __restrict__ o1, float* __restrict__ corr) {
  __shared__ float sc[TPn];
  __shared__ float red[256];
  __shared__ __align__(16) u16 Kt0[4096 / 2], Vt0[4096], Kt1[4096 / 2], Vt1[4096];
  __shared__ float mkS[64], skS[64], mvS[128], svS[128];
  int tid = threadIdx.x;
  int lane = tid & 63, w = tid >> 6;
  if (blockIdx.x >= 128) {
    // ---------------- PV branch
    int id = blockIdx.x - 128;
    int bh = id >> 2, dq = id & 3;
    int b = bh >> 3, h = bh & 7;
    const float* srow = scores + (size_t)bh * TPn;
    float4 z4 = *((const float4*)srow + tid);
    float z[4] = {z4.x, z4.y, z4.z, z4.w};
    float m = fmaxf(fmaxf(z[0], z[1]), fmaxf(z[2], z[3]));
#pragma unroll
    for (int off = 32; off; off >>= 1) m = fmaxf(m, __shfl_xor(m, off));
    if (lane == 0) red[w] = m;
    __syncthreads();
    m = fmaxf(fmaxf(red[0], red[1]), fmaxf(red[2], red[3]));
    float lsum = 0.f;
#pragma unroll
    for (int j = 0; j < 4; ++j) {
      float e = __expf(z[j] - m);   // padded t wrote -1e30 -> e==0
      sc[tid * 4 + j] = e;
      lsum += e;
    }
#pragma unroll
    for (int off = 32; off; off >>= 1) lsum += __shfl_xor(lsum, off);
    if (lane == 0) red[4 + w] = lsum;
    __syncthreads();
    float inv = 1.f / (red[4] + red[5] + red[6] + red[7]);
    // PV: lane dl handles d = dq*32+dl over t-slice of 128
    int dl = tid & 31, slice = tid >> 5;
    int d = dq * 32 + dl;
    const u16* Vr = mhT + ((size_t)(1 * Bn + b) * Hn + h) * Dn * TPn + (size_t)d * TPn + slice * 128;
    const float* at = sc + slice * 128;
    float a = 0.f;
#pragma unroll
    for (int i = 0; i < 16; ++i) {
      bf16x8 vv = *(const bf16x8*)(Vr + i * 8);
#pragma unroll
      for (int j = 0; j < 8; ++j) a += at[i * 8 + j] * (float)vv[j];
    }
    a += __shfl_xor(a, 32);              // sum slice pair within wave
    __syncthreads();                      // all inv-reads done before red reuse
    if (lane < 32) red[w * 32 + dl] = a;  // 4 wave-partials per dl
    __syncthreads();
    if (tid < 32)
      o1[((size_t)b * Hn + h) * Dn + dq * 32 + tid] =
          inv * (red[tid] + red[32 + tid] + red[64 + tid] + red[96 + tid]);
    return;
  }
  // ---------------- Gram-direct branch (2-way row split)
  int id = blockIdx.x;
  int bh = id & 63, rh = id >> 6;   // rh in [0,2): row-half
  int b = bh >> 3, h = bh & 7;
  const u16* Kb = mhT + ((size_t)(0 * Bn + b) * Hn + h) * Dn * TPn + (size_t)(rh * 64) * TPn;
  const u16* Vb = mhT + ((size_t)(1 * Bn + b) * Hn + h) * Dn * TPn;
  // stats (s1/s2 complete before this dispatch)
  if (tid < 64) {
    int dd = rh * 64 + tid;
    int sidx = ((0 * Bn + b) * Hn + h) * Dn + dd;
    float a1 = s1buf[sidx], a2 = s2buf[sidx];
    float mu = a1 / (float)Tn;
    float var = (a2 - a1 * a1 / (float)Tn) / (float)(Tn - 1);
    mkS[tid] = mu;
    skS[tid] = sqrtf(fmaxf(var, 0.f)) + 1e-9f;
  } else if (tid < 192) {
    int dd = tid - 64;
    int sidx = ((1 * Bn + b) * Hn + h) * Dn + dd;
    float a1 = s1buf[sidx], a2 = s2buf[sidx];
    float mu = a1 / (float)Tn;
    float var = (a2 - a1 * a1 / (float)Tn) / (float)(Tn - 1);
    mvS[dd] = mu;
    svS[dd] = sqrtf(fmaxf(var, 0.f)) + 1e-9f;
  }
  f32x4 acc[4][2];
#pragma unroll
  for (int mi = 0; mi < 4; ++mi)
#pragma unroll
    for (int ni = 0; ni < 2; ++ni) acc[mi][ni] = (f32x4){0.f, 0.f, 0.f, 0.f};
  int rowA = tid >> 2, partA = tid & 3;           // K rows 0..63 / V rows 0..63
  int rowV1 = 64 + (tid >> 2);                    // V rows 64..127
  int wbA = (w * 64) * 8;                         // wave-uniform elem base (w*512)
  int wbV1 = 2048 + (w * 64) * 8;

  auto STAGE = [&](int t0, u16* Kd, u16* Vd) {
    gload_lds16(Kb + (size_t)rowA * TPn + t0 + partA * 8, Kd + wbA);
    gload_lds16(Vb + (size_t)rowA * TPn + t0 + partA * 8, Vd + wbA);
    gload_lds16(Vb + (size_t)rowV1 * TPn + t0 + partA * 8, Vd + wbV1);
  };
  auto COMPUTE = [&](const u16* Kc, const u16* Vc) {
    bf16x8 af[4], bg[2];
#pragma unroll
    for (int mi = 0; mi < 4; ++mi)
      af[mi] = *(const bf16x8*)(Kc + (mi * 16 + (lane & 15)) * 32 + (lane >> 4) * 8);
#pragma unroll
    for (int ni = 0; ni < 2; ++ni)
      bg[ni] = *(const bf16x8*)(Vc + (w * 32 + ni * 16 + (lane & 15)) * 32 + (lane >> 4) * 8);
#pragma unroll
    for (int mi = 0; mi < 4; ++mi)
#pragma unroll
      for (int ni = 0; ni < 2; ++ni)
        acc[mi][ni] = __builtin_amdgcn_mfma_f32_16x16x32_bf16(af[mi], bg[ni], acc[mi][ni], 0, 0, 0);
  };

  STAGE(0, Kt0, Vt0);
  __syncthreads();  // also covers stats
  for (int s = 0; s < TPn; s += 64) {
    if (s + 32 < TPn) STAGE(s + 32, Kt1, Vt1);
    COMPUTE(Kt0, Vt0);
    __syncthreads();
    if (s + 64 < TPn) STAGE(s + 64, Kt0, Vt0);
    COMPUTE(Kt1, Vt1);
    __syncthreads();
  }
  const float invT = 1.f / (float)Tn;
#pragma unroll
  for (int mi = 0; mi < 4; ++mi)
#pragma unroll
    for (int ni = 0; ni < 2; ++ni)
#pragma unroll
      for (int r = 0; r < 4; ++r) {
        int ml = mi * 16 + (lane >> 4) * 4 + r;        // row-local 0..63
        int nn = w * 32 + ni * 16 + (lane & 15);       // col 0..127
        int mm = rh * 64 + ml;
        if (nn > mm) {
          float S = acc[mi][ni][r];
          float cv = (S - (float)Tn * mkS[ml] * mvS[nn]) * invT / (skS[ml] * svS[nn]);
          int cidx = mm * (2 * Dn - mm - 1) / 2 + (nn - mm - 1);
          corr[(size_t)bh * NCOR + cidx] = cv;
        }
      }
}

// ---------------------------------------------------------------- k5a: head proj
// block (ec 0..31, h fastest): 8 e-values per block, 8x8 reg accumulators.
// corr slab re-read /8 vs per-e blocks; h = blockIdx.x&7 makes corr[.,h] XCD-resident.
__global__ __launch_bounds__(256) void k5_proj(
    const float* __restrict__ corr, const float* __restrict__ Wproj,
    const float* __restrict__ bproj, float* __restrict__ outs) {
  __shared__ float red[256];
  int tid = threadIdx.x, lane = tid & 63, w = tid >> 6;
  int h = blockIdx.x & 7, ec = blockIdx.x >> 3;
  float acc[8][8];  // [ei][b]
#pragma unroll
  for (int ei = 0; ei < 8; ++ei)
#pragma unroll
    for (int b = 0; b < 8; ++b) acc[ei][b] = 0.f;
  for (int k = 0; k < 8; ++k) {
    int c4 = tid + k * 256;
    if (c4 < NCOR / 4) {
      float4 cv[8];
#pragma unroll
      for (int b = 0; b < 8; ++b)
        cv[b] = *((const float4*)(corr + ((size_t)b * Hn + h) * NCOR) + c4);
#pragma unroll
      for (int ei = 0; ei < 8; ++ei) {
        float4 wv = *((const float4*)(Wproj + ((size_t)h * En + ec * 8 + ei) * NCOR) + c4);
#pragma unroll
        for (int b = 0; b < 8; ++b)
          acc[ei][b] += wv.x * cv[b].x + wv.y * cv[b].y + wv.z * cv[b].z + wv.w * cv[b].w;
      }
    }
  }
  const float* af = &acc[0][0];
#pragma unroll
  for (int v = 0; v < 64; ++v) {
    float s = af[v];
#pragma unroll
    for (int off = 32; off; off >>= 1) s += __shfl_xor(s, off);
    if (lane == 0) red[w * 64 + v] = s;
  }
  __syncthreads();
  if (tid < 64) {
    int ei = tid >> 3, b = tid & 7;
    float s = red[tid] + red[64 + tid] + red[128 + tid] + red[192 + tid];
    outs[((size_t)b * Hn + h) * En + ec * 8 + ei] = s + bproj[h * En + ec * 8 + ei];
  }
}

// ---------------------------------------------------------------- k5b: final mix
__global__ __launch_bounds__(256) void k5_final(
    const float* __restrict__ outs, const float* __restrict__ o1,
    const float* __restrict__ WT, const float* __restrict__ bT,
    const float* __restrict__ Wp, const float* __restrict__ bp,
    float* __restrict__ out) {
  __shared__ float os[2048];
  __shared__ float o1s[1024];
  __shared__ float redF[256], redT[256];
  int tid = threadIdx.x;
  int b = blockIdx.x >> 3, ic = blockIdx.x & 7;
  for (int i = tid; i < 2048; i += 256) os[i] = outs[(size_t)b * 2048 + i];
  for (int i = tid; i < 1024; i += 256) o1s[i] = o1[(size_t)b * 1024 + i];
  __syncthreads();
  int il = tid >> 3, slice = tid & 7;
  int i = ic * 32 + il;
  const float* wpr = Wp + (size_t)i * 2048;
  const float* wtr = WT + (size_t)i * 1024;
  float aF = 0.f, aT = 0.f;
  for (int kk = 0; kk < 256; ++kk) { int j = kk * 8 + slice; aF += os[j] * wpr[j]; }
  for (int kk = 0; kk < 128; ++kk) { int j = kk * 8 + slice; aT += o1s[j] * wtr[j]; }
  redF[tid] = aF; redT[tid] = aT;
  __syncthreads();
  for (int s = 4; s > 0; s >>= 1) {
    if (slice < s) { redF[tid] += redF[tid + s]; redT[tid] += redT[tid + s]; }
    __syncthreads();
  }
  if (slice == 0) {
    float oF = redF[tid] + bp[i];
    float oT = redT[tid] + bT[i];
    out[(size_t)b * En + i] = 0.5f * oF + 0.5f * oT;
  }
}

// ---------------------------------------------------------------- launch
extern "C" void kernel_launch(void* const* d_in, const int* in_sizes, int n_in,
                              void* d_out, int out_size, void* d_ws, size_t ws_size,
                              hipStream_t stream) {
  const float* x     = (const float*)d_in[0];
  const float* wk    = (const float*)d_in[1];
  const float* wv    = (const float*)d_in[2];
  const float* q     = (const float*)d_in[3];
  const float* Wk    = (const float*)d_in[4];
  const float* bk    = (const float*)d_in[5];
  const float* Wv    = (const float*)d_in[6];
  const float* bv    = (const float*)d_in[7];
  const float* Wproj = (const float*)d_in[8];
  const float* bproj = (const float*)d_in[9];
  const float* WT    = (const float*)d_in[10];
  const float* bT    = (const float*)d_in[11];
  const float* Wp    = (const float*)d_in[12];
  const float* bp    = (const float*)d_in[13];
  float* out = (float*)d_out;

  char* ws = (char*)d_ws;
  size_t off = 0;
  auto alloc = [&](size_t bytes) { size_t p = off; off += (bytes + 255) & ~(size_t)255; return p; };
  u16*   Wbf    = (u16*)  (ws + alloc((size_t)2 * Hn * Dn * Fn * 2));
  u16*   mhT    = (u16*)  (ws + alloc((size_t)2 * Bn * Hn * Dn * TPn * 2));
  float* s1     = (float*)(ws + alloc((size_t)2 * Bn * Hn * Dn * 4));
  float* s2     = (float*)(ws + alloc((size_t)2 * Bn * Hn * Dn * 4));
  float* o1     = (float*)(ws + alloc((size_t)Bn * Hn * Dn * 4));
  float* corr   = (float*)(ws + alloc((size_t)Bn * Hn * NCOR * 4));
  float* outs   = (float*)(ws + alloc((size_t)Bn * Hn * En * 4));
  float* scores = (float*)(ws + alloc((size_t)Bn * Hn * TPn * 4));
  size_t fixed = off;
  size_t per_b = (size_t)2 * Hn * TPn * Fn * 2;  // kv_raw per batch: 24 MB
  int BG = 8;
  while (BG > 1 && fixed + (size_t)BG * per_b > ws_size) BG >>= 1;
  u16* kv_raw = (u16*)(ws + fixed);

  for (int b0 = 0; b0 < Bn; b0 += BG) {
    k1_raw<<<dim3(32, 24, BG), 256, 0, stream>>>(x, wk, wv, Wk, Wv, kv_raw, Wbf, s1, s2, b0, BG);
    k2_gemm<<<dim3(Hn * BG, 8, 2), 256, 0, stream>>>(kv_raw, Wbf, bk, bv, q, mhT, s1, s2,
                                                     scores, b0, BG);
  }
  k34<<<384, 256, 0, stream>>>(mhT, scores, s1, s2, o1, corr);
  k5_proj<<<256, 256, 0, stream>>>(corr, Wproj, bproj, outs);
  k5_final<<<64, 256, 0, stream>>>(outs, o1, WT, bT, Wp, bp, out);
}